// Round 1
// baseline (165.633 us; speedup 1.0000x reference)
//
#include <hip/hip_runtime.h>

// NCC loss, fused single pass. Layout [n][1][d][h][w], n=2, d=160, h=192, w=192, f32.
// R6: aligned LDS window reads. R5 read 12 floats (3x ds_read_b128) per row/array to
//   use 8: window cols 4tx-2..4tx+5 were misaligned by 2 vs the tile layout
//   (col c <-> w = wbase-4+c). R6 shifts the layout to col c <-> w = wbase-2+c so the
//   window is exactly cols 4tx..4tx+7 -> 2x aligned ds_read_b128, zero waste
//   (-33% LDS read bytes and instructions; conflict cycles track b128 count).
//   EDGE CLAMP TRAP: global_load_lds DMA segs are 16B-granular with CLAMPED global
//   base (per m104/m108 the LDS dest is lane-linear; per-lane masking is forbidden).
//   With the -2 layout, the clamped seg at wbase==0 loads w=(0,1,2,3) into cols 0-3
//   (expected -2,-1,0,1): cols 2,3 are mis-shifted REAL data. Same at wbase==128,
//   c16=16: cols 64-67 hold w=188..191 (expected 190..193). Both are fixed by an
//   in-register permute at the only threads that read those cols:
//     bx0,tx0 : a[2]=a[0]; a[3]=a[1]; a[0]=a[1]=0;   (w=-2,-1 are zero-pad)
//     bx2,tx15: a[4]=a[6]; a[5]=a[7]; a[6]=a[7]=0;   (w=192,193 are zero-pad)
//   All other R5 structure kept: double-buffered DMA staging (all lanes always issue
//   with clamped addresses; only the r=2 tail mask lane<52 keeps lane 0 active),
//   H-OOB rows skipped in compute, D-OOB slices skipped wave-uniformly, ring in
//   registers, NO occupancy clamp in __launch_bounds__ (R3's (256,4) spilled).

namespace {
constexpr int Wd = 192, Hd = 192, Dd = 160;
constexpr int SH = 192;              // h stride (floats)
constexpr int SD = 192 * 192;        // d stride
constexpr long SN = (long)SD * Dd;   // n stride
constexpr int CD = 6;                // d outputs per chunk; T = CD+4 = 10
constexpr int NCHUNK = 27;           // ceil(160/6)
constexpr int TROW = 72;             // LDS row stride (floats), unpadded (DMA lane map)
constexpr int TILEF = 2 * 20 * TROW; // floats per buffer (2880)
constexpr float INV_V = 1.0f / 125.0f;
constexpr float EPSf = 1e-5f;

__device__ __forceinline__ void wslide(const float h[8], float o[4]) {
  float s0 = h[0] + h[1] + h[2] + h[3] + h[4];
  float s1 = s0 - h[0] + h[5];
  float s2 = s1 - h[1] + h[6];
  float s3 = s2 - h[2] + h[7];
  o[0] = s0; o[1] = s1; o[2] = s2; o[3] = s3;
}

__device__ __forceinline__ void gl_lds16(const float* g, float* l) {
  __builtin_amdgcn_global_load_lds(
      (const __attribute__((address_space(1))) void*)g,
      (__attribute__((address_space(3))) void*)l, 16, 0, 0);
}
} // namespace

__global__ __launch_bounds__(256) void ncc_fused(const float* __restrict__ I,
                                                 const float* __restrict__ Jv,
                                                 float* __restrict__ out) {
  __shared__ float tile[2][TILEF];   // 23.04 KB double buffer
  __shared__ float red[4];

  const int tid = threadIdx.x;
  const int tx = tid & 15;        // w-run index (4 outputs each)
  const int ty = tid >> 4;        // h row within 16-tall tile
  const int wbase = blockIdx.x * 64;
  const int hbase = blockIdx.y * 16;
  const int n  = blockIdx.z / NCHUNK;
  const int d_lo = (blockIdx.z % NCHUNK) * CD;

  const float* Ib = I  + (long)n * SN;
  const float* Jb = Jv + (long)n * SN;

  // ---- staging descriptors: 720 16B-segs; wave w owns segs [w*180,(w+1)*180) ----
  // seg = arr*360 + row*18 + c16 ; LDS byte-offset = seg*16 (consecutive per lane)
  // layout: LDS col c  <->  global w = wbase - 2 + c   (R6: shifted +2 vs R5)
  const int wave = tid >> 6, lane = tid & 63;
  const int arr = wave >> 1;                       // waves 0,1 -> I ; 2,3 -> J
  const float* gsrc = arr ? Jb : Ib;
  int goff[3]; int loff[3]; bool on[3];
  #pragma unroll
  for (int r = 0; r < 3; ++r) {
    const int seg = wave * 180 + r * 64 + lane;
    on[r] = (r < 2) || (lane < 52);                // 180 = 2*64 + 52 (lane 0 stays active)
    const int rem = seg - arr * 360;
    const int row = rem / 18, c16 = rem % 18;
    const int hh = hbase + row - 2;
    const int hc = min(max(hh, 0), Hd - 1);        // CLAMP, never mask
    const int gw = wbase - 2 + c16 * 4;
    const int gc = min(max(gw, 0), Wd - 4);
    goff[r] = hc * SH + gc;
    loff[r] = seg * 4;                             // float offset
  }

  // ---- stage slice d_lo-2 into buffer 0 ----
  {
    const int s0 = d_lo - 2;
    if (s0 >= 0 && s0 < Dd) {
      const float* base = gsrc + (long)s0 * SD;
      #pragma unroll
      for (int r = 0; r < 3; ++r) if (on[r]) gl_lds16(base + goff[r], &tile[0][loff[r]]);
    }
  }
  __syncthreads();

  // Edge fixup flags (see header comment): only these 2 thread-columns touch the
  // clamp-corrupted cols, and the true values live in other slots of the same read.
  const bool fixl = (wbase == 0)   && (tx == 0);
  const bool fixr = (wbase == 128) && (tx == 15);

  float ring[5][5][4];  // [phase][channel:{I,J,II,JJ,IJ}][k]
  float acc = 0.0f;

  constexpr int T = CD + 4; // 10 steps; output d = d_lo + t - 4 for t>=4
  for (int t0 = 0; t0 < T; t0 += 5) {
    #pragma unroll
    for (int p = 0; p < 5; ++p) {             // phase = t % 5
      const int t = t0 + p;
      const int s = d_lo - 2 + t;             // slice in current buffer

      // ---- DMA slice s+1 into the other buffer (overlaps this step's compute) ----
      {
        const int sn = s + 1;
        if ((t + 1) < T && sn >= 0 && sn < Dd) {   // wave-uniform condition
          const float* base = gsrc + (long)sn * SD;
          float* dst = &tile[(t + 1) & 1][0];
          #pragma unroll
          for (int r = 0; r < 3; ++r) if (on[r]) gl_lds16(base + goff[r], dst + loff[r]);
        }
      }

      // ---- H-window accumulate from current buffer ----
      float hsI[8], hsJ[8], hsII[8], hsJJ[8], hsIJ[8];
      #pragma unroll
      for (int c = 0; c < 8; ++c) {
        hsI[c] = 0.f; hsJ[c] = 0.f; hsII[c] = 0.f; hsJJ[c] = 0.f; hsIJ[c] = 0.f;
      }
      if (s >= 0 && s < Dd) {
        const float* bufc = &tile[t & 1][0];
        #pragma unroll
        for (int dh = 0; dh < 5; ++dh) {
          const int rrow = ty + dh;            // rows ty..ty+4 <-> hh = hbase+ty-2+dh
          const int hh = hbase + rrow - 2;
          if (hh >= 0 && hh < Hd) {            // skip clamped-duplicate halo rows
            const float* pa = bufc + rrow * TROW + 4 * tx;  // cols 4tx..4tx+7, 16B-aligned
            const float* pb = pa + 20 * TROW;  // J array
            float a[8], b[8];
            ((float4*)a)[0] = ((const float4*)pa)[0];
            ((float4*)a)[1] = ((const float4*)pa)[1];
            ((float4*)b)[0] = ((const float4*)pb)[0];
            ((float4*)b)[1] = ((const float4*)pb)[1];
            if (fixl) { a[2]=a[0]; a[3]=a[1]; a[0]=0.f; a[1]=0.f;
                        b[2]=b[0]; b[3]=b[1]; b[0]=0.f; b[1]=0.f; }
            if (fixr) { a[4]=a[6]; a[5]=a[7]; a[6]=0.f; a[7]=0.f;
                        b[4]=b[6]; b[5]=b[7]; b[6]=0.f; b[7]=0.f; }
            #pragma unroll
            for (int c = 0; c < 8; ++c) {
              const float x = a[c], y = b[c];  // cols w0-2..w0+5
              hsI[c]  += x;
              hsJ[c]  += y;
              hsII[c] = fmaf(x, x, hsII[c]);
              hsJJ[c] = fmaf(y, y, hsJJ[c]);
              hsIJ[c] = fmaf(x, y, hsIJ[c]);
            }
          }
        }
      }

      // ---- W-window sliding sums -> ring ----
      wslide(hsI,  ring[p][0]);
      wslide(hsJ,  ring[p][1]);
      wslide(hsII, ring[p][2]);
      wslide(hsJJ, ring[p][3]);
      wslide(hsIJ, ring[p][4]);

      // ---- D-window + cc ----
      const int d = d_lo + t - 4;
      if (t >= 4 && d < Dd) {
        #pragma unroll
        for (int k = 0; k < 4; ++k) {
          float SI = 0.f, SJ = 0.f, SII = 0.f, SJJ = 0.f, SIJ = 0.f;
          #pragma unroll
          for (int q = 0; q < 5; ++q) {
            SI  += ring[q][0][k];
            SJ  += ring[q][1][k];
            SII += ring[q][2][k];
            SJJ += ring[q][3][k];
            SIJ += ring[q][4][k];
          }
          const float cross = SIJ - SI * SJ * INV_V;
          const float vI    = SII - SI * SI * INV_V;
          const float vJ    = SJJ - SJ * SJ * INV_V;
          acc += cross * cross / (vI * vJ + EPSf);
        }
      }

      __syncthreads();  // drains DMA for s+1; reads of current buffer done
    }
  }

  // ---- block reduction -> single atomic per block ----
  #pragma unroll
  for (int off = 32; off > 0; off >>= 1) acc += __shfl_xor(acc, off, 64);
  if ((tid & 63) == 0) red[tid >> 6] = acc;
  __syncthreads();
  if (tid == 0) {
    const float total = red[0] + red[1] + red[2] + red[3];
    atomicAdd(out, total * (-1.0f / 11796480.0f)); // -mean over 2*160*192*192
  }
}

extern "C" void kernel_launch(void* const* d_in, const int* in_sizes, int n_in,
                              void* d_out, int out_size, void* d_ws, size_t ws_size,
                              hipStream_t stream) {
  const float* I = (const float*)d_in[0];
  const float* J = (const float*)d_in[1];
  float* out = (float*)d_out;
  hipMemsetAsync(out, 0, sizeof(float), stream);
  dim3 grid(3, 12, 2 * NCHUNK); // W tiles * H tiles * (n x 27 d-chunks of 6)
  ncc_fused<<<grid, 256, 0, stream>>>(I, J, out);
}